// Round 5
// baseline (130.841 us; speedup 1.0000x reference)
//
#include <hip/hip_runtime.h>
#include <hip/hip_bf16.h>

#define NB 32
#define NN 2048
#define DD 64
#define SQC 0.4246613965f  // sqrt(0.125 * LOG2E); applied to both Q and K

typedef __attribute__((ext_vector_type(8))) short short8;
typedef __attribute__((ext_vector_type(4))) float f32x4;
typedef __attribute__((ext_vector_type(16))) float f32x16;
typedef __attribute__((ext_vector_type(4))) unsigned uint4v;
typedef __attribute__((ext_vector_type(4))) int int4v;

#define MFMA32B(A, B, C) \
  __builtin_amdgcn_mfma_f32_32x32x16_bf16((A), (B), (C), 0, 0, 0)

#define GLOAD_LDS16(gp, lp)                                                   \
  __builtin_amdgcn_global_load_lds(                                          \
      (const __attribute__((address_space(1))) void*)(gp),                   \
      (__attribute__((address_space(3))) void*)(lp), 16, 0, 0)

__device__ __forceinline__ short f2bf(float x) {
  __bf16 h = (__bf16)x;
  return __builtin_bit_cast(short, h);
}

__device__ __forceinline__ float fast_exp2(float x) {
#if __has_builtin(__builtin_amdgcn_exp2f)
  return __builtin_amdgcn_exp2f(x);
#else
  return exp2f(x);
#endif
}

// round-to-nearest bf16 pack of two positive floats: lo -> low short
__device__ __forceinline__ unsigned pack_bf16_rnd(float lo, float hi) {
  unsigned ulo = __builtin_bit_cast(unsigned, lo) + 0x8000u;
  unsigned uhi = __builtin_bit_cast(unsigned, hi) + 0x8000u;
  return __builtin_amdgcn_perm(uhi, ulo, 0x07060302u);
}

// ---- 32x32x16 layouts (A: m=l&31, k=(l>>5)*8+j; B: n=l&31, k=(l>>5)*8+j;
// C: col=l&31, row=(reg&3)+8*(reg>>2)+4*(l>>5) [m74/m101-verified]).
// Key permutation: A-row m of a K-fragment holds actual key key_of_row(m):
#define KEY_OF_ROW(m) \
  ((((m) >> 3) & 1) * 16 + (((m) >> 2) & 1) * 8 + ((m) >> 4) * 4 + ((m) & 3))
// With this, lane-half h's QK output regs r^ map to key
// koff(r^,h) = 16*((r^>>2)&1) + 8h + 4*(r^>>3) + (r^&3), and the PV
// B-operands are simply pc0 = [e0..e3,e8..e11] (keys c*32+8h+0..7) and
// pc1 = [e4..e7,e12..e15] (keys c*32+16+8h+0..7) — zero runtime shuffles,
// V stored in NATURAL key order, Q and the output need no permutation.

// ---------- prep: per 32-key chunk, 8 fragment units of 1 KB:
// units 0..3  : K A-frags (dc=unit), rows permuted by KEY_OF_ROW, *SQC
// units 4..7  : V A-frags (4+dh*2+kh), natural key order, transposed
// plus adj -> 16-bit-per-(q,h,chunk) masks packed as uint32 per chunk-pair,
// laid out mbw[(h*32+cp)*2048 + q] for coalesced main-loop reads.
__global__ __launch_bounds__(256) void prep_fused(
    const float* __restrict__ x, const int* __restrict__ adj,
    short* __restrict__ img, unsigned* __restrict__ mbw) {
  const int tid = threadIdx.x;
  const int c = blockIdx.x;   // 64-key window -> new chunks 2c, 2c+1
  const int b = blockIdx.y;

  // K units
#pragma unroll
  for (int i = 0; i < 2; ++i) {
    const int kc = tid + i * 256;
    const int u8 = kc >> 6, l = kc & 63;
    const int chl = u8 >> 2, dc = u8 & 3;
    const int m = l & 31, hA = l >> 5;
    const int grow = c * 64 + chl * 32 + KEY_OF_ROW(m);
    const float* src = x + ((size_t)(b * NN + grow)) * DD + dc * 16 + 8 * hA;
    float4 f0 = ((const float4*)src)[0];
    float4 f1 = ((const float4*)src)[1];
    short8 v;
    v[0] = f2bf(f0.x * SQC); v[1] = f2bf(f0.y * SQC);
    v[2] = f2bf(f0.z * SQC); v[3] = f2bf(f0.w * SQC);
    v[4] = f2bf(f1.x * SQC); v[5] = f2bf(f1.y * SQC);
    v[6] = f2bf(f1.z * SQC); v[7] = f2bf(f1.w * SQC);
    *(short8*)&img[((size_t)(b * 64 + 2 * c + chl) * 8 + dc) * 512 + l * 8] = v;
  }
  // V units (transposed gather, natural key order)
#pragma unroll
  for (int i = 0; i < 2; ++i) {
    const int vc = tid + i * 256;
    const int u8 = vc >> 6, l = vc & 63;
    const int chl = u8 >> 2, sub = u8 & 3;
    const int dh = sub >> 1, kh = sub & 1;
    const int d = dh * 32 + (l & 31);
    const int key0 = c * 64 + chl * 32 + kh * 16 + 8 * (l >> 5);
    short8 o;
#pragma unroll
    for (int j = 0; j < 8; ++j)
      o[j] = f2bf(x[((size_t)(b * NN + key0 + j)) * DD + d]);
    *(short8*)&img[((size_t)(b * 64 + 2 * c + chl) * 8 + 4 + sub) * 512 +
                   l * 8] = o;
  }

  // masks: block owns 2 q-rows; thread = (qrow, h, cp)
  const int R0 = (b * 32 + c) * 2;
  if (tid < 128) {
    const int qrow = R0 + (tid >> 6);
    const int h = (tid >> 5) & 1;
    const int cp = tid & 31;
    unsigned mw = 0;
#pragma unroll
    for (int c01 = 0; c01 < 2; ++c01)
#pragma unroll
      for (int b4 = 0; b4 < 2; ++b4) {
        const int* ap =
            adj + (size_t)qrow * NN + cp * 64 + c01 * 32 + b4 * 16 + 8 * h;
        int4v a0 = *(const int4v*)ap;
        int4v a1 = *(const int4v*)(ap + 4);
#pragma unroll
        for (int j = 0; j < 8; ++j) {
          const int av = (j < 4) ? a0[j & 3] : a1[j & 3];
          const int rh = 8 * (j >> 2) + 4 * b4 + (j & 3);
          mw |= (av > 0 ? 1u : 0u) << (16 * c01 + rh);
        }
      }
    mbw[(size_t)(h * 32 + cp) * NN + qrow] = mw;
  }
}

// One pipeline phase (chunk c, P = c&3): [counted vmcnt][raw barrier]
// [stage chunk c+3 -> ring (P+3)&3][setprio(1) 32x32 compute][setprio(0)]
#define PHASE_BODY(P, VM, DO_STAGE, CSTAGE, MW)                             \
  {                                                                         \
    asm volatile("s_waitcnt vmcnt(" VM ")" ::: "memory");                   \
    __builtin_amdgcn_s_barrier();                                           \
    if (DO_STAGE) {                                                         \
      const short* gs = img_b + (size_t)(CSTAGE) * 4096 + l * 8;            \
      GLOAD_LDS16(gs + (2 * w) * 512, &sI[((P) + 3) & 3][(2 * w) * 512]);   \
      GLOAD_LDS16(gs + (2 * w + 1) * 512,                                   \
                  &sI[((P) + 3) & 3][(2 * w + 1) * 512]);                   \
    }                                                                       \
    __builtin_amdgcn_s_setprio(1);                                          \
    const short* ring = sI[(P) & 3];                                        \
    const unsigned wm16 = ((MW) >> (((P) & 1) * 16)) & 0xffffu;             \
    f32x16 s;                                                               \
    _Pragma("unroll") for (int z = 0; z < 16; ++z) s[z] = 0.f;              \
    _Pragma("unroll") for (int dc = 0; dc < 4; ++dc)                        \
        s = MFMA32B(*(const short8*)&ring[dc * 512 + l * 8], qf[dc], s);    \
    float e[16];                                                            \
    _Pragma("unroll") for (int r = 0; r < 16; ++r) {                        \
      float ev = fast_exp2(s[r]);                                           \
      e[r] = ((wm16 >> r) & 1u) ? ev : 0.f;                                 \
    }                                                                       \
    uint4v p0, p1;                                                          \
    p0[0] = pack_bf16_rnd(e[0], e[1]);                                      \
    p0[1] = pack_bf16_rnd(e[2], e[3]);                                      \
    p0[2] = pack_bf16_rnd(e[8], e[9]);                                      \
    p0[3] = pack_bf16_rnd(e[10], e[11]);                                    \
    p1[0] = pack_bf16_rnd(e[4], e[5]);                                      \
    p1[1] = pack_bf16_rnd(e[6], e[7]);                                      \
    p1[2] = pack_bf16_rnd(e[12], e[13]);                                    \
    p1[3] = pack_bf16_rnd(e[14], e[15]);                                    \
    short8 pc0 = __builtin_bit_cast(short8, p0);                            \
    short8 pc1 = __builtin_bit_cast(short8, p1);                            \
    acl = MFMA32B(ones8, pc0, acl);                                         \
    acl = MFMA32B(ones8, pc1, acl);                                         \
    acc[0] = MFMA32B(*(const short8*)&ring[4 * 512 + l * 8], pc0, acc[0]);  \
    acc[0] = MFMA32B(*(const short8*)&ring[5 * 512 + l * 8], pc1, acc[0]);  \
    acc[1] = MFMA32B(*(const short8*)&ring[6 * 512 + l * 8], pc0, acc[1]);  \
    acc[1] = MFMA32B(*(const short8*)&ring[7 * 512 + l * 8], pc1, acc[1]);  \
    __builtin_amdgcn_s_setprio(0);                                          \
  }

// ---------- main: 32x32x16 pipeline. 512 blocks x 256 thr; wave owns 32 q
// (one 32x32 C-col-tile), block covers 128 q. LDS bytes per FLOP halved vs
// the 16x16 version (8 KB reads per 32q*32k*64d instead of 16 KB).
// beta&7 = XCD; 4 batches/XCD keep img (2 MB) + mbw L2-resident.
__global__ __launch_bounds__(256, 2) void gat_flash13(
    const float* __restrict__ x, const short* __restrict__ img,
    const unsigned* __restrict__ mbw, float* __restrict__ out) {
  __shared__ short sI[4][4096];  // ring of 4 x 8 KB (8 units of 1 KB)

  const int beta = blockIdx.x;
  const int xcd = beta & 7;
  const int idx = beta >> 3;       // 0..63
  const int qg = idx & 15;         // 128-row q-group
  const int b = xcd * 4 + (idx >> 4);

  const int tid = threadIdx.x;
  const int w = tid >> 6;
  const int l = tid & 63;
  const int h = l >> 5;
  const int q = qg * 128 + w * 32 + (l & 31);

  const short* img_b = img + (size_t)b * 64 * 8 * 512;

  // Q B-frags from x (scaled by SQC): qf[dc], elem j = Q[q, dc*16+8h+j]*SQC
  short8 qf[4];
  {
    const float* qs = x + ((size_t)(b * NN + q)) * DD + 8 * h;
#pragma unroll
    for (int dc = 0; dc < 4; ++dc) {
      float4 f0 = ((const float4*)(qs + dc * 16))[0];
      float4 f1 = ((const float4*)(qs + dc * 16))[1];
      short8 v;
      v[0] = f2bf(f0.x * SQC); v[1] = f2bf(f0.y * SQC);
      v[2] = f2bf(f0.z * SQC); v[3] = f2bf(f0.w * SQC);
      v[4] = f2bf(f1.x * SQC); v[5] = f2bf(f1.y * SQC);
      v[6] = f2bf(f1.z * SQC); v[7] = f2bf(f1.w * SQC);
      qf[dc] = v;
    }
  }

  f32x16 acc[2], acl;
#pragma unroll
  for (int z = 0; z < 16; ++z) { acc[0][z] = 0.f; acc[1][z] = 0.f; acl[z] = 0.f; }

  short8 ones8;
#pragma unroll
  for (int j = 0; j < 8; ++j) ones8[j] = 0x3F80;

  const unsigned* mbase = mbw + (size_t)h * 32 * NN + q;
  unsigned mwA = mbase[0];
  unsigned mwB = mbase[NN];

  // prologue: stage chunks 0,1,2 into rings 0,1,2 (2 units per wave each)
#pragma unroll
  for (int sc = 0; sc < 3; ++sc) {
    const short* gs = img_b + (size_t)sc * 4096 + l * 8;
    GLOAD_LDS16(gs + (2 * w) * 512, &sI[sc][(2 * w) * 512]);
    GLOAD_LDS16(gs + (2 * w + 1) * 512, &sI[sc][(2 * w + 1) * 512]);
  }

  for (int M = 0; M < 15; ++M) {
    PHASE_BODY(0, "4", true, 4 * M + 3, mwA);
    PHASE_BODY(1, "4", true, 4 * M + 4, mwA);
    const unsigned nA = mbase[(size_t)(2 * M + 2) * NN];
    const unsigned nB = mbase[(size_t)(2 * M + 3) * NN];
    PHASE_BODY(2, "4", true, 4 * M + 5, mwB);
    PHASE_BODY(3, "4", true, 4 * M + 6, mwB);
    mwA = nA;
    mwB = nB;
  }
  // tail: chunks 60..63 (masks cp=30,31 already in mwA/mwB)
  PHASE_BODY(0, "4", true, 63, mwA);
  PHASE_BODY(1, "4", false, 0, mwA);
  PHASE_BODY(2, "2", false, 0, mwB);
  PHASE_BODY(3, "0", false, 0, mwB);

  // ---- epilogue: C col = q (natural), row r+8*qd+4h -> d = dh*32+row ----
  const float inv = 1.0f / acl[0];
  float* op = out + ((size_t)(b * NN + q)) * DD;
#pragma unroll
  for (int dh = 0; dh < 2; ++dh)
#pragma unroll
    for (int qd = 0; qd < 4; ++qd) {
      float4 o;
      o.x = acc[dh][qd * 4 + 0] * inv;
      o.y = acc[dh][qd * 4 + 1] * inv;
      o.z = acc[dh][qd * 4 + 2] * inv;
      o.w = acc[dh][qd * 4 + 3] * inv;
      *(float4*)(op + dh * 32 + 8 * qd + 4 * h) = o;
    }
}

extern "C" void kernel_launch(void* const* d_in, const int* in_sizes, int n_in,
                              void* d_out, int out_size, void* d_ws,
                              size_t ws_size, hipStream_t stream) {
  const float* x = (const float*)d_in[0];
  const int* adj = (const int*)d_in[1];
  float* out = (float*)d_out;

  short* img = (short*)d_ws;  // 16 MB fragment-major image
  unsigned* mbw = (unsigned*)(img + (size_t)NB * 64 * 8 * 512);  // 512 KB

  prep_fused<<<dim3(32, NB), 256, 0, stream>>>(x, adj, img, mbw);
  gat_flash13<<<512, 256, 0, stream>>>(x, img, mbw, out);
}

// Round 6
// 125.597 us; speedup vs baseline: 1.0418x; 1.0418x over previous
//
#include <hip/hip_runtime.h>
#include <hip/hip_bf16.h>

#define NB 32
#define NN 2048
#define DD 64
#define SQC 0.4246613965f  // sqrt(0.125 * LOG2E); applied to both Q and K

typedef __attribute__((ext_vector_type(8))) short short8;
typedef __attribute__((ext_vector_type(16))) float f32x16;
typedef __attribute__((ext_vector_type(4))) unsigned uint4v;
typedef __attribute__((ext_vector_type(4))) int int4v;

#define MFMA32B(A, B, C) \
  __builtin_amdgcn_mfma_f32_32x32x16_bf16((A), (B), (C), 0, 0, 0)

#define GLOAD_LDS16(gp, lp)                                                   \
  __builtin_amdgcn_global_load_lds(                                          \
      (const __attribute__((address_space(1))) void*)(gp),                   \
      (__attribute__((address_space(3))) void*)(lp), 16, 0, 0)

__device__ __forceinline__ short f2bf(float x) {
  __bf16 h = (__bf16)x;
  return __builtin_bit_cast(short, h);
}

__device__ __forceinline__ float fast_exp2(float x) {
#if __has_builtin(__builtin_amdgcn_exp2f)
  return __builtin_amdgcn_exp2f(x);
#else
  return exp2f(x);
#endif
}

// ---- 32x32x16 layouts (A: m=l&31, k=(l>>5)*8+j; B: n=l&31, k=(l>>5)*8+j;
// C: col=l&31, row=(reg&3)+8*(reg>>2)+4*(l>>5)).
// Key permutation: A-row m of a K-fragment holds actual key KEY_OF_ROW(m):
#define KEY_OF_ROW(m) \
  ((((m) >> 3) & 1) * 16 + (((m) >> 2) & 1) * 8 + ((m) >> 4) * 4 + ((m) & 3))
// QK output reg r (lane-half h) maps to key koff(r,h) =
// 16*((r>>2)&1) + 8h + 4*(r>>3) + (r&3); pc0 = regs {0..3,8..11} = keys
// 8h+0..7, pc1 = regs {4..7,12..15} = keys 16+8h+0..7. V natural key order.

// ---------- fused prep: fragment-major bf16 image (K scaled+permuted, V
// transposed) + batch-independent expanded byte-masks mexp:
// mexp[(qg*64+c)*2+h][ql] = uint4; byte t of word wd = 0xFF iff
// adj[qg*128+ql][c*32 + 16*(wd&1)+8h+4*(wd>>1)+t] > 0.  (4 MB total)
__global__ __launch_bounds__(256) void prep_fused(
    const float* __restrict__ x, const int* __restrict__ adj,
    short* __restrict__ img, uint4v* __restrict__ mexp) {
  const int tid = threadIdx.x;
  const int c = blockIdx.x;   // 64-key window -> chunks 2c, 2c+1
  const int b = blockIdx.y;

  // K units (scaled by SQC, permuted rows)
#pragma unroll
  for (int i = 0; i < 2; ++i) {
    const int kc = tid + i * 256;
    const int u8 = kc >> 6, l = kc & 63;
    const int chl = u8 >> 2, dc = u8 & 3;
    const int m = l & 31, hA = l >> 5;
    const int grow = c * 64 + chl * 32 + KEY_OF_ROW(m);
    const float* src = x + ((size_t)(b * NN + grow)) * DD + dc * 16 + 8 * hA;
    float4 f0 = ((const float4*)src)[0];
    float4 f1 = ((const float4*)src)[1];
    short8 v;
    v[0] = f2bf(f0.x * SQC); v[1] = f2bf(f0.y * SQC);
    v[2] = f2bf(f0.z * SQC); v[3] = f2bf(f0.w * SQC);
    v[4] = f2bf(f1.x * SQC); v[5] = f2bf(f1.y * SQC);
    v[6] = f2bf(f1.z * SQC); v[7] = f2bf(f1.w * SQC);
    *(short8*)&img[((size_t)(b * 64 + 2 * c + chl) * 8 + dc) * 512 + l * 8] = v;
  }
  // V units (transposed gather, natural key order)
#pragma unroll
  for (int i = 0; i < 2; ++i) {
    const int vc = tid + i * 256;
    const int u8 = vc >> 6, l = vc & 63;
    const int chl = u8 >> 2, sub = u8 & 3;
    const int dh = sub >> 1, kh = sub & 1;
    const int d = dh * 32 + (l & 31);
    const int key0 = c * 64 + chl * 32 + kh * 16 + 8 * (l >> 5);
    short8 o;
#pragma unroll
    for (int j = 0; j < 8; ++j)
      o[j] = f2bf(x[((size_t)(b * NN + key0 + j)) * DD + d]);
    *(short8*)&img[((size_t)(b * 64 + 2 * c + chl) * 8 + 4 + sub) * 512 +
                   l * 8] = o;
  }

  // expanded masks: block (c,b) -> tile (qg = b>>1, cm = 2c + (b&1))
  if (tid < 128) {
    const int qg = b >> 1;
    const int cm = blockIdx.x * 2 + (b & 1);
    const int ql = tid;
    const int* ap = adj + (size_t)(qg * 128 + ql) * NN + cm * 32;
    int4v av[8];
#pragma unroll
    for (int j = 0; j < 8; ++j) av[j] = *(const int4v*)(ap + j * 4);
#pragma unroll
    for (int h = 0; h < 2; ++h) {
      uint4v mv;
#pragma unroll
      for (int wd = 0; wd < 4; ++wd) {
        unsigned word = 0;
#pragma unroll
        for (int t = 0; t < 4; ++t) {
          const int K = 16 * (wd & 1) + 8 * h + 4 * (wd >> 1) + t;
          word |= (av[K >> 2][K & 3] > 0 ? 0xFFu : 0u) << (8 * t);
        }
        mv[wd] = word;
      }
      mexp[((size_t)(qg * 64 + cm) * 2 + h) * 128 + ql] = mv;
    }
  }
}

// One phase: [vmcnt(3)][barrier][snapshot mask][stage KV c+2 -> ring PSTG]
// [prefetch mask c+2 -> MBUF][setprio(1) compute chunk c][setprio(0)].
// Per-phase VMEM = 2 gload_lds + 1 dwordx4, always ordered kv-then-mask, so
// vmcnt(3) (= one younger phase) guarantees chunk c's KV and mask complete.
#define PHASE_BODY(RING, PSTG, MBUF, VM, DO_STAGE, CSTAGE)                   \
  {                                                                          \
    asm volatile("s_waitcnt vmcnt(" VM ")" ::: "memory");                    \
    __builtin_amdgcn_s_barrier();                                            \
    const uint4v mcur = MBUF;                                                \
    if (DO_STAGE) {                                                          \
      const short* gs = img_b + (size_t)(CSTAGE)*4096 + l * 8;               \
      GLOAD_LDS16(gs + (2 * w) * 512, &sI[PSTG][(2 * w) * 512]);             \
      GLOAD_LDS16(gs + (2 * w + 1) * 512, &sI[PSTG][(2 * w + 1) * 512]);     \
      asm volatile("" ::: "memory");                                         \
      MBUF = *(const uint4v*)(mpt + (size_t)(CSTAGE)*4096);                  \
      asm volatile("" ::: "memory");                                         \
    }                                                                        \
    __builtin_amdgcn_s_setprio(1);                                           \
    const short* ring = sI[RING];                                            \
    f32x16 s = MFMA32B(*(const short8*)&ring[0 * 512 + l * 8], qf[0], fz);   \
    s = MFMA32B(*(const short8*)&ring[1 * 512 + l * 8], qf[1], s);           \
    s = MFMA32B(*(const short8*)&ring[2 * 512 + l * 8], qf[2], s);           \
    s = MFMA32B(*(const short8*)&ring[3 * 512 + l * 8], qf[3], s);           \
    float e[16];                                                             \
    _Pragma("unroll") for (int r = 0; r < 16; ++r) e[r] = fast_exp2(s[r]);   \
    short8 pc0, pc1;                                                         \
    pc0[0] = f2bf(e[0]);  pc0[1] = f2bf(e[1]);                               \
    pc0[2] = f2bf(e[2]);  pc0[3] = f2bf(e[3]);                               \
    pc0[4] = f2bf(e[8]);  pc0[5] = f2bf(e[9]);                               \
    pc0[6] = f2bf(e[10]); pc0[7] = f2bf(e[11]);                              \
    pc1[0] = f2bf(e[4]);  pc1[1] = f2bf(e[5]);                               \
    pc1[2] = f2bf(e[6]);  pc1[3] = f2bf(e[7]);                               \
    pc1[4] = f2bf(e[12]); pc1[5] = f2bf(e[13]);                              \
    pc1[6] = f2bf(e[14]); pc1[7] = f2bf(e[15]);                              \
    uint4v u0 = __builtin_bit_cast(uint4v, pc0);                             \
    uint4v u1 = __builtin_bit_cast(uint4v, pc1);                             \
    u0[0] &= __builtin_amdgcn_perm(0u, mcur[0], 0x01010000u);                \
    u0[1] &= __builtin_amdgcn_perm(0u, mcur[0], 0x03030202u);                \
    u0[2] &= __builtin_amdgcn_perm(0u, mcur[2], 0x01010000u);                \
    u0[3] &= __builtin_amdgcn_perm(0u, mcur[2], 0x03030202u);                \
    u1[0] &= __builtin_amdgcn_perm(0u, mcur[1], 0x01010000u);                \
    u1[1] &= __builtin_amdgcn_perm(0u, mcur[1], 0x03030202u);                \
    u1[2] &= __builtin_amdgcn_perm(0u, mcur[3], 0x01010000u);                \
    u1[3] &= __builtin_amdgcn_perm(0u, mcur[3], 0x03030202u);                \
    pc0 = __builtin_bit_cast(short8, u0);                                    \
    pc1 = __builtin_bit_cast(short8, u1);                                    \
    acl = MFMA32B(ones8, pc0, acl);                                          \
    acl = MFMA32B(ones8, pc1, acl);                                          \
    acc[0] = MFMA32B(*(const short8*)&ring[4 * 512 + l * 8], pc0, acc[0]);   \
    acc[0] = MFMA32B(*(const short8*)&ring[5 * 512 + l * 8], pc1, acc[0]);   \
    acc[1] = MFMA32B(*(const short8*)&ring[6 * 512 + l * 8], pc0, acc[1]);   \
    acc[1] = MFMA32B(*(const short8*)&ring[7 * 512 + l * 8], pc1, acc[1]);   \
    __builtin_amdgcn_s_setprio(0);                                           \
  }

// ---------- main: 32x32x16 pipeline, ring-3 of 8 KB KV units (24 KB LDS),
// masks as expanded bytes prefetched 2 phases ahead into registers.
// 512 blocks x 256 thr (2 blocks/CU); beta&7 = XCD, 4 batches/XCD.
__global__ __launch_bounds__(256, 2) void gat_flash14(
    const float* __restrict__ x, const short* __restrict__ img,
    const char* __restrict__ mexp, float* __restrict__ out) {
  __shared__ short sI[3][4096];

  const int beta = blockIdx.x;
  const int xcd = beta & 7;
  const int idx = beta >> 3;       // 0..63
  const int qg = idx & 15;         // 128-row q-group
  const int b = xcd * 4 + (idx >> 4);

  const int tid = threadIdx.x;
  const int w = tid >> 6;
  const int l = tid & 63;
  const int h = l >> 5;
  const int ql = w * 32 + (l & 31);
  const int q = qg * 128 + ql;

  const short* img_b = img + (size_t)b * 64 * 8 * 512;
  const char* mpt =
      mexp + ((size_t)(qg * 128 + h) * 128 + ql) * 16;  // chunk stride 4096 B

  // Q B-frags from x (scaled by SQC): qf[dc], elem j = Q[q, dc*16+8h+j]*SQC
  short8 qf[4];
  {
    const float* qs = x + ((size_t)(b * NN + q)) * DD + 8 * h;
#pragma unroll
    for (int dc = 0; dc < 4; ++dc) {
      float4 f0 = ((const float4*)(qs + dc * 16))[0];
      float4 f1 = ((const float4*)(qs + dc * 16))[1];
      short8 v;
      v[0] = f2bf(f0.x * SQC); v[1] = f2bf(f0.y * SQC);
      v[2] = f2bf(f0.z * SQC); v[3] = f2bf(f0.w * SQC);
      v[4] = f2bf(f1.x * SQC); v[5] = f2bf(f1.y * SQC);
      v[6] = f2bf(f1.z * SQC); v[7] = f2bf(f1.w * SQC);
      qf[dc] = v;
    }
  }

  f32x16 acc[2], acl, fz;
#pragma unroll
  for (int z = 0; z < 16; ++z) {
    acc[0][z] = 0.f; acc[1][z] = 0.f; acl[z] = 0.f; fz[z] = 0.f;
  }

  short8 ones8;
#pragma unroll
  for (int j = 0; j < 8; ++j) ones8[j] = 0x3F80;

  uint4v m0, m1;

  // prologue: [kv0, m0, kv1, m1] so vmcnt(3) at phase 0 covers kv0+m0
  {
    const short* g0 = img_b + l * 8;
    GLOAD_LDS16(g0 + (2 * w) * 512, &sI[0][(2 * w) * 512]);
    GLOAD_LDS16(g0 + (2 * w + 1) * 512, &sI[0][(2 * w + 1) * 512]);
    asm volatile("" ::: "memory");
    m0 = *(const uint4v*)(mpt);
    asm volatile("" ::: "memory");
    const short* g1 = img_b + 4096 + l * 8;
    GLOAD_LDS16(g1 + (2 * w) * 512, &sI[1][(2 * w) * 512]);
    GLOAD_LDS16(g1 + (2 * w + 1) * 512, &sI[1][(2 * w + 1) * 512]);
    asm volatile("" ::: "memory");
    m1 = *(const uint4v*)(mpt + 4096);
    asm volatile("" ::: "memory");
  }

  // 10 macro-iters x 6 phases (lcm of ring-3 and mask-parity-2): c=0..59
  for (int M = 0; M < 10; ++M) {
    const int c0 = 6 * M;
    PHASE_BODY(0, 2, m0, "3", true, c0 + 2);
    PHASE_BODY(1, 0, m1, "3", true, c0 + 3);
    PHASE_BODY(2, 1, m0, "3", true, c0 + 4);
    PHASE_BODY(0, 2, m1, "3", true, c0 + 5);
    PHASE_BODY(1, 0, m0, "3", true, c0 + 6);
    PHASE_BODY(2, 1, m1, "3", true, c0 + 7);
  }
  // tail: c = 60, 61 (stage 62, 63), 62, 63 (no stage)
  PHASE_BODY(0, 2, m0, "3", true, 62);
  PHASE_BODY(1, 0, m1, "3", true, 63);
  PHASE_BODY(2, 1, m0, "3", false, 0);
  PHASE_BODY(0, 2, m1, "0", false, 0);

  // ---- epilogue: C col = q (natural), row r = (r&3)+8*(r>>2)+4h -> d ----
  const float inv = 1.0f / acl[0];
  float* op = out + ((size_t)(b * NN + q)) * DD;
#pragma unroll
  for (int dh = 0; dh < 2; ++dh)
#pragma unroll
    for (int qd = 0; qd < 4; ++qd) {
      float4 o;
      o.x = acc[dh][qd * 4 + 0] * inv;
      o.y = acc[dh][qd * 4 + 1] * inv;
      o.z = acc[dh][qd * 4 + 2] * inv;
      o.w = acc[dh][qd * 4 + 3] * inv;
      *(float4*)(op + dh * 32 + 8 * qd + 4 * h) = o;
    }
}

extern "C" void kernel_launch(void* const* d_in, const int* in_sizes, int n_in,
                              void* d_out, int out_size, void* d_ws,
                              size_t ws_size, hipStream_t stream) {
  const float* x = (const float*)d_in[0];
  const int* adj = (const int*)d_in[1];
  float* out = (float*)d_out;

  short* img = (short*)d_ws;                                   // 16 MB
  uint4v* mexp = (uint4v*)(img + (size_t)NB * 64 * 8 * 512);   // 4 MB

  prep_fused<<<dim3(32, NB), 256, 0, stream>>>(x, adj, img, mexp);
  gat_flash14<<<512, 256, 0, stream>>>(x, img, (const char*)mexp, out);
}